// Round 11
// baseline (73.718 us; speedup 1.0000x reference)
//
#include <hip/hip_runtime.h>
#include <math.h>

// Spectral NS projection step, 512x512 fp32 periodic — radix-8 register FFT.
//
// v11: v10 with the two transposes moved from the LOAD side to the STORE
// side. Rationale: gathers (64-line scatter reads) sit on the dependent-load
// critical path — the wave stalls on the slowest of 64 transactions before
// its FFT can start (at 2 waves/CU nothing hides it). Stores are
// fire-and-forget and drain asynchronously at kernel end. With the
// XCD-contiguous maps, every scattered 128B line (ZT[kj][i..i+15],
// WR[i][cw..cw+15]) is written entirely by ONE XCD's blocks -> write-combines
// in that XCD's L2, no partial-line amplification (v5's failure mode was
// scatters WITHOUT the XCD grouping). Every dependent LOAD in the pipeline
// is now fully coalesced.
//
//  kA (512x64) : row i=(b&7)*64+(b>>3); stencil + fwd row FFT;
//                scatter-store ZT[kj*512+i] (transposed, async).
//  kB (256x128): base col c0=(b&7)*32+(b>>3); wave w: col {c0, 512-c0}
//                (c0==0 -> {0,256}); COALESCED load of ZT row cw; fwd FFT;
//                conj(Z(-k)) via zst LDS (mirror wave); exact-Jacobi
//                multiplier (beta chain precomputed in load shadow);
//                inv FFT; scatter-store WR[i*512+cw] (transposed, async).
//  kC (512x64) : row i; COALESCED load of WR row i; inv row FFT;
//                recompute p; out = p - grad(phi) (nontemporal).
//
// Multiplier (exact identity): M = r^1000 - (1-r^1000)/(4-s), r=s/4,
//   s=2cos ai+2cos aj;  4-s = 4(sin^2(ai/2)+sin^2(aj/2)) (cancellation-free)
//   W(k) = (beta/2)[(sx^2+sy^2) Z(k) + (sx+i sy)^2 conj(Z(-k))], beta=-10M/512^2
// sin/cos over k stepped by pi/8 Givens rotation (1 sincosf per thread).
//
// Stockham radix-8, 3 stages, reads always buf[t+64m] (conflict-free);
// LDS scatter writes padded by idx+(idx>>3) -> near-uniform bank usage.
// fft512 uses wave_barrier (wave-private buffers, per-wave in-order DS);
// exactly one real __syncthreads in the whole pipeline (kB mirror stage).

#define HH 512
#define WW 512
#define NCELL (HH * WW)
#define NU_C 0.1f
#define PI_F 3.14159265358979323846f
#define PADDED 576   // pad(511)=574

#define WBAR() __builtin_amdgcn_wave_barrier()

__device__ __forceinline__ int padi(int i) { return i + (i >> 3); }

__device__ __forceinline__ float2 cadd(float2 a, float2 b) { return make_float2(a.x + b.x, a.y + b.y); }
__device__ __forceinline__ float2 csub(float2 a, float2 b) { return make_float2(a.x - b.x, a.y - b.y); }
__device__ __forceinline__ float2 cmul(float2 a, float2 b) {
    return make_float2(a.x * b.x - a.y * b.y, a.x * b.y + a.y * b.x);
}

// twiddle tables are stored FORWARD (cis(-theta)); inverse conjugates on use
template <int S>
__device__ __forceinline__ float2 cmul_tw(float2 a, float2 w) {
    float wy = (S < 0) ? w.y : -w.y;
    return make_float2(a.x * w.x - a.y * wy, a.x * wy + a.y * w.x);
}

// 8-point DFT, S=-1 forward (e^{-2pi i km/8}), S=+1 inverse
template <int S>
__device__ __forceinline__ void bfly8(float2 r[8]) {
    const float c = 0.70710678118654752f;
    const float s = (float)S;
    float2 e0 = cadd(r[0], r[4]), f0 = csub(r[0], r[4]);
    float2 e1 = cadd(r[2], r[6]), f1 = csub(r[2], r[6]);
    float2 g0 = cadd(r[1], r[5]), h0 = csub(r[1], r[5]);
    float2 g1 = cadd(r[3], r[7]), h1 = csub(r[3], r[7]);
    float2 E0 = cadd(e0, e1), E2 = csub(e0, e1);
    float2 if1 = make_float2(-s * f1.y, s * f1.x);       // s*i*f1
    float2 E1 = cadd(f0, if1), E3 = csub(f0, if1);
    float2 O0 = cadd(g0, g1), O2 = csub(g0, g1);
    float2 ih1 = make_float2(-s * h1.y, s * h1.x);
    float2 O1 = cadd(h0, ih1), O3 = csub(h0, ih1);
    float2 t1 = make_float2(c * (O1.x - s * O1.y), c * (O1.y + s * O1.x)); // W8^s1 * O1
    float2 t2 = make_float2(-s * O2.y, s * O2.x);                          // s*i*O2
    float2 t3 = make_float2(-c * (O3.x + s * O3.y), -c * (O3.y - s * O3.x));
    r[0] = cadd(E0, O0); r[4] = csub(E0, O0);
    r[1] = cadd(E1, t1); r[5] = csub(E1, t1);
    r[2] = cadd(E2, t2); r[6] = csub(E2, t2);
    r[3] = cadd(E3, t3); r[7] = csub(E3, t3);
}

struct Twid { float2 s1[8]; float2 s2[8]; };

__device__ __forceinline__ void make_tw(Twid& tw, int t) {
    float sn, cs;
    sincosf(-2.0f * PI_F * (float)(t & 7) * (1.0f / 64.0f), &sn, &cs);
    float2 T1 = make_float2(cs, sn);
    tw.s1[0] = make_float2(1.0f, 0.0f);
#pragma unroll
    for (int m = 1; m < 8; ++m) tw.s1[m] = cmul(tw.s1[m - 1], T1);
    sincosf(-2.0f * PI_F * (float)t * (1.0f / 512.0f), &sn, &cs);
    float2 T2 = make_float2(cs, sn);
    tw.s2[0] = make_float2(1.0f, 0.0f);
#pragma unroll
    for (int m = 1; m < 8; ++m) tw.s2[m] = cmul(tw.s2[m - 1], T2);
}

// 512-pt Stockham radix-8, one wave, wave-private LDS buffers.
// Cross-lane exchange ordering: wave_barrier (compiler fence) + CDNA's
// in-order per-wave DS pipeline; no block barrier needed.
template <int S>
__device__ __forceinline__ void fft512(float2 r[8], const Twid& tw,
                                       float2* b0, float2* b1, int t) {
    bfly8<S>(r);
#pragma unroll
    for (int k = 0; k < 8; ++k) b0[padi(8 * t + k)] = r[k];
    WBAR();
#pragma unroll
    for (int m = 0; m < 8; ++m) r[m] = b0[padi(t + 64 * m)];
#pragma unroll
    for (int m = 1; m < 8; ++m) r[m] = cmul_tw<S>(r[m], tw.s1[m]);
    bfly8<S>(r);
    int base = ((t >> 3) << 6) + (t & 7);
#pragma unroll
    for (int k = 0; k < 8; ++k) b1[padi(base + 8 * k)] = r[k];
    WBAR();
#pragma unroll
    for (int m = 0; m < 8; ++m) r[m] = b1[padi(t + 64 * m)];
#pragma unroll
    for (int m = 1; m < 8; ++m) r[m] = cmul_tw<S>(r[m], tw.s2[m]);
    bfly8<S>(r);
}

// stencil: partial for both fields at row i, cols t+64m (bitwise-shared by kA/kC)
__device__ __forceinline__ void stencil_row(const float* __restrict__ X,
                                            const float* __restrict__ F,
                                            int i, int t, float p0r[8], float p1r[8]) {
    const int ip = (i + 1) & 511, im = (i + 511) & 511;
    const float* X0 = X;
    const float* X1 = X + NCELL;
#pragma unroll
    for (int m = 0; m < 8; ++m) {
        int j = t + 64 * m;
        int jp = (j + 1) & 511, jm = (j + 511) & 511;
        float x0c = X0[i * WW + j], x1c = X1[i * WW + j];
        float aip = X0[ip * WW + j], aim = X0[im * WW + j];
        float ajp = X0[i * WW + jp], ajm = X0[i * WW + jm];
        p0r[m] = -(x0c * (aip - aim) * 0.5f + x1c * (ajp - ajm) * 0.5f)
               + NU_C * (aip + aim + ajp + ajm - 4.0f * x0c) + F[i * WW + j];
        float bip = X1[ip * WW + j], bim = X1[im * WW + j];
        float bjp = X1[i * WW + jp], bjm = X1[i * WW + jm];
        p1r[m] = -(x0c * (bip - bim) * 0.5f + x1c * (bjp - bjm) * 0.5f)
               + NU_C * (bip + bim + bjp + bjm - 4.0f * x1c) + F[NCELL + i * WW + j];
    }
}

__device__ __forceinline__ float beta_of(float qs) {
    float rN;              // r^1000 = |r|^1000, r = 1-qs
    if (qs < 1.0f)      rN = expf(1000.0f * log1pf(-qs));
    else if (qs > 1.0f) rN = expf(1000.0f * logf(qs - 1.0f));
    else                rN = 0.0f;
    float M = rN - (1.0f - rN) / (4.0f * qs);
    return -10.0f * M * (1.0f / (512.0f * 512.0f));
}

// --------------------------------------------- phase A: stencil + row FFT
__global__ __launch_bounds__(64) void kA(const float* __restrict__ X,
                                         const float* __restrict__ F,
                                         float2* __restrict__ ZT) {
    __shared__ float2 b0[PADDED], b1[PADDED];
    const int b = blockIdx.x, t = threadIdx.x;
    const int i = (b & 7) * 64 + (b >> 3);    // XCD x owns rows [64x,64x+64)
    // stencil loads issue first; twiddle gen overlaps their latency
    float p0r[8], p1r[8];
    stencil_row(X, F, i, t, p0r, p1r);
    Twid tw; make_tw(tw, t);
    float2 r[8];
#pragma unroll
    for (int m = 0; m < 8; ++m) r[m] = make_float2(p0r[m], p1r[m]);
    fft512<-1>(r, tw, b0, b1, t);
    // transposed scatter ZT[kj][i]: async, write-combines in-XCD (line =
    // 16 consecutive i of one kj, all produced by this XCD's row span)
#pragma unroll
    for (int k = 0; k < 8; ++k) ZT[(t + 64 * k) * 512 + i] = r[k];
}

// ------- phase B: mirror-pair col FFT + multiplier + inverse col FFT
// base col c0=(b&7)*32+(b>>3): XCD x owns cols [32x,32x+32) + mirror span.
__global__ __launch_bounds__(128) void kB(const float2* __restrict__ ZT,
                                          float2* __restrict__ WR) {
    __shared__ float2 b0[2][PADDED], b1[2][PADDED];
    __shared__ float2 zst[2][512];            // spectrum stage (mirror access)
    const int b = blockIdx.x;
    const int w = threadIdx.x >> 6, t = threadIdx.x & 63;
    const int c0 = (b & 7) * 32 + (b >> 3);   // 0..255, all distinct
    const int cw = (c0 == 0) ? (w ? 256 : 0) : (w ? 512 - c0 : c0);
    const int mw = (c0 == 0) ? w : (w ^ 1);
    float2 r[8];
    // COALESCED load: column cw of Z = row cw of ZT
#pragma unroll
    for (int m = 0; m < 8; ++m) r[m] = ZT[cw * 512 + t + 64 * m];

    // ---- precompute (in the load shadow): twiddles + ALL multiplier
    // constants, incl. the log/exp beta chain (index-only, off critical path)
    Twid tw; make_tw(tw, t);
    float shy, chy;
    sincosf(PI_F * (float)cw * (1.0f / 512.0f), &shy, &chy);
    const float sy = 2.0f * shy * chy;   // sin(2 pi cw/512)
    const float qy = shy * shy;          // sin^2(pi cw/512)
    float sxk[8], betak[8];
    {
        float sh, ch;
        sincosf(PI_F * (float)t * (1.0f / 512.0f), &sh, &ch);
        const float c8 = 0.92387953251128675613f;  // cos(pi/8)
        const float s8 = 0.38268343236508977173f;  // sin(pi/8)
#pragma unroll
        for (int k = 0; k < 8; ++k) {
            int ki = t + 64 * k;
            sxk[k] = 2.0f * sh * ch;
            float qs = sh * sh + qy;
            betak[k] = (ki == 0 && cw == 0) ? 0.0f : beta_of(qs);
            float nch = ch * c8 - sh * s8;         // advance angle by pi/8
            sh = sh * c8 + ch * s8;
            ch = nch;
        }
    }

    fft512<-1>(r, tw, b0[w], b1[w], t);
    // stage spectrum in its own buffer (inverse FFT never touches zst)
#pragma unroll
    for (int k = 0; k < 8; ++k) zst[w][t + 64 * k] = r[k];
    __syncthreads();   // the ONLY block barrier: sibling's stage visible

    // multiplier: pure mul/add + LDS mirror reads (short inter-FFT path)
#pragma unroll
    for (int k = 0; k < 8; ++k) {
        int ki = t + 64 * k;
        int mi = (HH - ki) & 511;
        float2 z  = r[k];                      // Z(k) (own spectrum, regs)
        float2 zc = zst[mw][mi];               // Z(-k) from mirror wave's stage
        float sx = sxk[k];
        float su  = sx * sx + sy * sy;
        float u2x = sx * sx - sy * sy;
        float u2y = 2.0f * sx * sy;
        float cx = zc.x, cy = -zc.y;           // conj(Z(-k))
        float tx = u2x * cx - u2y * cy;
        float ty = u2x * cy + u2y * cx;
        float bh = 0.5f * betak[k];
        r[k] = make_float2(bh * (su * z.x + tx), bh * (su * z.y + ty));
    }
    // no second barrier: inv FFT uses only wave-private b0[w]/b1[w]
    fft512<1>(r, tw, b0[w], b1[w], t);
    // transposed scatter WR[i][cw]: async, write-combines in-XCD (line =
    // 16 consecutive cols of one row, col spans 32-aligned per XCD)
#pragma unroll
    for (int k = 0; k < 8; ++k) WR[(t + 64 * k) * 512 + cw] = r[k];
}

// --------------------------------------- phase C: inverse row FFT + output
__global__ __launch_bounds__(64) void kC(const float2* __restrict__ WR,
                                         const float* __restrict__ X,
                                         const float* __restrict__ F,
                                         float* __restrict__ out) {
    __shared__ float2 b0[PADDED], b1[PADDED];
    const int b = blockIdx.x, t = threadIdx.x;
    const int i = (b & 7) * 64 + (b >> 3);    // XCD x owns rows [64x,64x+64)
    float2 r[8];
    // COALESCED load of WR row i, issued first; twiddle gen + stencil
    // recompute hide under the load latency
#pragma unroll
    for (int m = 0; m < 8; ++m) r[m] = WR[i * 512 + t + 64 * m];
    Twid tw; make_tw(tw, t);
    float p0r[8], p1r[8];
    stencil_row(X, F, i, t, p0r, p1r);         // bitwise-identical to kA's p
    fft512<1>(r, tw, b0, b1, t);
#pragma unroll
    for (int k = 0; k < 8; ++k) {
        int j = t + 64 * k;
        __builtin_nontemporal_store(p0r[k] - r[k].x, &out[i * WW + j]);
        __builtin_nontemporal_store(p1r[k] - r[k].y, &out[NCELL + i * WW + j]);
    }
}

// ---------------------------------------------------------------------------
extern "C" void kernel_launch(void* const* d_in, const int* in_sizes, int n_in,
                              void* d_out, int out_size, void* d_ws, size_t ws_size,
                              hipStream_t stream) {
    const float* X = (const float*)d_in[1];
    const float* F = (const float*)d_in[2];
    float* out = (float*)d_out;
    float* ws  = (float*)d_ws;

    float2* ZT = (float2*)ws;                 // NCELL float2 (2 MB), [kj][i]
    float2* WR = ZT + NCELL;                  // NCELL float2 (2 MB), [i][kj]

    kA<<<dim3(512), dim3(64),  0, stream>>>(X, F, ZT);
    kB<<<dim3(256), dim3(128), 0, stream>>>(ZT, WR);
    kC<<<dim3(512), dim3(64),  0, stream>>>(WR, X, F, out);
}

// Round 12
// 72.612 us; speedup vs baseline: 1.0152x; 1.0152x over previous
//
#include <hip/hip_runtime.h>
#include <math.h>

// Spectral NS projection step, 512x512 fp32 periodic — radix-8 register FFT.
//
// v12 == v10 (measured best, 72.46us): restoration after v11's store-side
// transpose experiment regressed (73.7us). See journal: the wall is
// ~41us harness poison-fill (fixed) + ~31us of three latency-bound kernels;
// all structural alternatives (fusion+grid-sync, software barriers, ILP-2,
// store-side transposes) measured net-negative.
//
//  - fft512 uses __builtin_amdgcn_wave_barrier() (compile-time fence, 0
//    instructions): Stockham exchange buffers are WAVE-PRIVATE and CDNA DS
//    ops complete in program order within a wave.
//  - kB: spectrum staged in separate zst[2][512]; exactly ONE real
//    __syncthreads in the whole pipeline.
//  - kB: beta/log-exp chain + Givens terms precomputed in the gather shadow.
//  - kC: recomputes p (bitwise-identical stencil), nontemporal out stores.
//  - XCD-contiguous maps: i=(b&7)*64+(b>>3), c0=(b&7)*32+(b>>3) keep the
//    16-line cacheline groups of each transposed gather XCD-local.
//
//  kA (512x64) : row i; stencil + fwd row FFT; Zt row-major coalesced.
//  kB (256x128): wave w: col {c0, 512-c0} (c0==0 -> {0,256}); gather col
//                from Zt; fwd FFT; conj(Z(-k)) via zst (mirror wave);
//                exact-1000-step-Jacobi multiplier; inv FFT; W1 col-major.
//  kC (512x64) : gather row i from W1; inv row FFT; recompute p;
//                out = p - grad(phi) (nontemporal).
//
// Multiplier (exact identity): M = r^1000 - (1-r^1000)/(4-s), r=s/4,
//   s=2cos ai+2cos aj;  4-s = 4(sin^2(ai/2)+sin^2(aj/2)) (cancellation-free)
//   W(k) = (beta/2)[(sx^2+sy^2) Z(k) + (sx+i sy)^2 conj(Z(-k))], beta=-10M/512^2
// sin/cos over k stepped by pi/8 Givens rotation (1 sincosf per thread).
//
// Stockham radix-8, 3 stages, reads always buf[t+64m] (conflict-free);
// LDS scatter writes padded by idx+(idx>>3) -> near-uniform bank usage.

#define HH 512
#define WW 512
#define NCELL (HH * WW)
#define NU_C 0.1f
#define PI_F 3.14159265358979323846f
#define PADDED 576   // pad(511)=574

#define WBAR() __builtin_amdgcn_wave_barrier()

__device__ __forceinline__ int padi(int i) { return i + (i >> 3); }

__device__ __forceinline__ float2 cadd(float2 a, float2 b) { return make_float2(a.x + b.x, a.y + b.y); }
__device__ __forceinline__ float2 csub(float2 a, float2 b) { return make_float2(a.x - b.x, a.y - b.y); }
__device__ __forceinline__ float2 cmul(float2 a, float2 b) {
    return make_float2(a.x * b.x - a.y * b.y, a.x * b.y + a.y * b.x);
}

// twiddle tables are stored FORWARD (cis(-theta)); inverse conjugates on use
template <int S>
__device__ __forceinline__ float2 cmul_tw(float2 a, float2 w) {
    float wy = (S < 0) ? w.y : -w.y;
    return make_float2(a.x * w.x - a.y * wy, a.x * wy + a.y * w.x);
}

// 8-point DFT, S=-1 forward (e^{-2pi i km/8}), S=+1 inverse
template <int S>
__device__ __forceinline__ void bfly8(float2 r[8]) {
    const float c = 0.70710678118654752f;
    const float s = (float)S;
    float2 e0 = cadd(r[0], r[4]), f0 = csub(r[0], r[4]);
    float2 e1 = cadd(r[2], r[6]), f1 = csub(r[2], r[6]);
    float2 g0 = cadd(r[1], r[5]), h0 = csub(r[1], r[5]);
    float2 g1 = cadd(r[3], r[7]), h1 = csub(r[3], r[7]);
    float2 E0 = cadd(e0, e1), E2 = csub(e0, e1);
    float2 if1 = make_float2(-s * f1.y, s * f1.x);       // s*i*f1
    float2 E1 = cadd(f0, if1), E3 = csub(f0, if1);
    float2 O0 = cadd(g0, g1), O2 = csub(g0, g1);
    float2 ih1 = make_float2(-s * h1.y, s * h1.x);
    float2 O1 = cadd(h0, ih1), O3 = csub(h0, ih1);
    float2 t1 = make_float2(c * (O1.x - s * O1.y), c * (O1.y + s * O1.x)); // W8^s1 * O1
    float2 t2 = make_float2(-s * O2.y, s * O2.x);                          // s*i*O2
    float2 t3 = make_float2(-c * (O3.x + s * O3.y), -c * (O3.y - s * O3.x));
    r[0] = cadd(E0, O0); r[4] = csub(E0, O0);
    r[1] = cadd(E1, t1); r[5] = csub(E1, t1);
    r[2] = cadd(E2, t2); r[6] = csub(E2, t2);
    r[3] = cadd(E3, t3); r[7] = csub(E3, t3);
}

struct Twid { float2 s1[8]; float2 s2[8]; };

__device__ __forceinline__ void make_tw(Twid& tw, int t) {
    float sn, cs;
    sincosf(-2.0f * PI_F * (float)(t & 7) * (1.0f / 64.0f), &sn, &cs);
    float2 T1 = make_float2(cs, sn);
    tw.s1[0] = make_float2(1.0f, 0.0f);
#pragma unroll
    for (int m = 1; m < 8; ++m) tw.s1[m] = cmul(tw.s1[m - 1], T1);
    sincosf(-2.0f * PI_F * (float)t * (1.0f / 512.0f), &sn, &cs);
    float2 T2 = make_float2(cs, sn);
    tw.s2[0] = make_float2(1.0f, 0.0f);
#pragma unroll
    for (int m = 1; m < 8; ++m) tw.s2[m] = cmul(tw.s2[m - 1], T2);
}

// 512-pt Stockham radix-8, one wave, wave-private LDS buffers.
// Cross-lane exchange ordering: wave_barrier (compiler fence) + CDNA's
// in-order per-wave DS pipeline; no block barrier needed.
template <int S>
__device__ __forceinline__ void fft512(float2 r[8], const Twid& tw,
                                       float2* b0, float2* b1, int t) {
    bfly8<S>(r);
#pragma unroll
    for (int k = 0; k < 8; ++k) b0[padi(8 * t + k)] = r[k];
    WBAR();
#pragma unroll
    for (int m = 0; m < 8; ++m) r[m] = b0[padi(t + 64 * m)];
#pragma unroll
    for (int m = 1; m < 8; ++m) r[m] = cmul_tw<S>(r[m], tw.s1[m]);
    bfly8<S>(r);
    int base = ((t >> 3) << 6) + (t & 7);
#pragma unroll
    for (int k = 0; k < 8; ++k) b1[padi(base + 8 * k)] = r[k];
    WBAR();
#pragma unroll
    for (int m = 0; m < 8; ++m) r[m] = b1[padi(t + 64 * m)];
#pragma unroll
    for (int m = 1; m < 8; ++m) r[m] = cmul_tw<S>(r[m], tw.s2[m]);
    bfly8<S>(r);
}

// stencil: partial for both fields at row i, cols t+64m (bitwise-shared by kA/kC)
__device__ __forceinline__ void stencil_row(const float* __restrict__ X,
                                            const float* __restrict__ F,
                                            int i, int t, float p0r[8], float p1r[8]) {
    const int ip = (i + 1) & 511, im = (i + 511) & 511;
    const float* X0 = X;
    const float* X1 = X + NCELL;
#pragma unroll
    for (int m = 0; m < 8; ++m) {
        int j = t + 64 * m;
        int jp = (j + 1) & 511, jm = (j + 511) & 511;
        float x0c = X0[i * WW + j], x1c = X1[i * WW + j];
        float aip = X0[ip * WW + j], aim = X0[im * WW + j];
        float ajp = X0[i * WW + jp], ajm = X0[i * WW + jm];
        p0r[m] = -(x0c * (aip - aim) * 0.5f + x1c * (ajp - ajm) * 0.5f)
               + NU_C * (aip + aim + ajp + ajm - 4.0f * x0c) + F[i * WW + j];
        float bip = X1[ip * WW + j], bim = X1[im * WW + j];
        float bjp = X1[i * WW + jp], bjm = X1[i * WW + jm];
        p1r[m] = -(x0c * (bip - bim) * 0.5f + x1c * (bjp - bjm) * 0.5f)
               + NU_C * (bip + bim + bjp + bjm - 4.0f * x1c) + F[NCELL + i * WW + j];
    }
}

__device__ __forceinline__ float beta_of(float qs) {
    float rN;              // r^1000 = |r|^1000, r = 1-qs
    if (qs < 1.0f)      rN = expf(1000.0f * log1pf(-qs));
    else if (qs > 1.0f) rN = expf(1000.0f * logf(qs - 1.0f));
    else                rN = 0.0f;
    float M = rN - (1.0f - rN) / (4.0f * qs);
    return -10.0f * M * (1.0f / (512.0f * 512.0f));
}

// --------------------------------------------- phase A: stencil + row FFT
__global__ __launch_bounds__(64) void kA(const float* __restrict__ X,
                                         const float* __restrict__ F,
                                         float2* __restrict__ Zt) {
    __shared__ float2 b0[PADDED], b1[PADDED];
    const int b = blockIdx.x, t = threadIdx.x;
    const int i = (b & 7) * 64 + (b >> 3);    // XCD x owns rows [64x,64x+64)
    // stencil loads issue first; twiddle gen overlaps their latency
    float p0r[8], p1r[8];
    stencil_row(X, F, i, t, p0r, p1r);
    Twid tw; make_tw(tw, t);
    float2 r[8];
#pragma unroll
    for (int m = 0; m < 8; ++m) r[m] = make_float2(p0r[m], p1r[m]);
    fft512<-1>(r, tw, b0, b1, t);
    // ROW-major coalesced spectrum store (transpose deferred to kB's gather)
#pragma unroll
    for (int k = 0; k < 8; ++k) Zt[i * 512 + t + 64 * k] = r[k];
}

// ------- phase B: mirror-pair col FFT + multiplier + inverse col FFT
// base col c0=(b&7)*32+(b>>3): XCD x owns cols [32x,32x+32) + mirror span.
__global__ __launch_bounds__(128) void kB(const float2* __restrict__ Zt,
                                          float2* __restrict__ W1) {
    __shared__ float2 b0[2][PADDED], b1[2][PADDED];
    __shared__ float2 zst[2][512];            // spectrum stage (mirror access)
    const int b = blockIdx.x;
    const int w = threadIdx.x >> 6, t = threadIdx.x & 63;
    const int c0 = (b & 7) * 32 + (b >> 3);   // 0..255, all distinct
    const int cw = (c0 == 0) ? (w ? 256 : 0) : (w ? 512 - c0 : c0);
    const int mw = (c0 == 0) ? w : (w ^ 1);
    float2 r[8];
    // gather column cw from row-major Zt (16-col cacheline groups XCD-local)
#pragma unroll
    for (int m = 0; m < 8; ++m) r[m] = Zt[(t + 64 * m) * 512 + cw];

    // ---- precompute (in the gather shadow): twiddles + ALL multiplier
    // constants, incl. the log/exp beta chain (index-only, off critical path)
    Twid tw; make_tw(tw, t);
    float shy, chy;
    sincosf(PI_F * (float)cw * (1.0f / 512.0f), &shy, &chy);
    const float sy = 2.0f * shy * chy;   // sin(2 pi cw/512)
    const float qy = shy * shy;          // sin^2(pi cw/512)
    float sxk[8], betak[8];
    {
        float sh, ch;
        sincosf(PI_F * (float)t * (1.0f / 512.0f), &sh, &ch);
        const float c8 = 0.92387953251128675613f;  // cos(pi/8)
        const float s8 = 0.38268343236508977173f;  // sin(pi/8)
#pragma unroll
        for (int k = 0; k < 8; ++k) {
            int ki = t + 64 * k;
            sxk[k] = 2.0f * sh * ch;
            float qs = sh * sh + qy;
            betak[k] = (ki == 0 && cw == 0) ? 0.0f : beta_of(qs);
            float nch = ch * c8 - sh * s8;         // advance angle by pi/8
            sh = sh * c8 + ch * s8;
            ch = nch;
        }
    }

    fft512<-1>(r, tw, b0[w], b1[w], t);
    // stage spectrum in its own buffer (inverse FFT never touches zst)
#pragma unroll
    for (int k = 0; k < 8; ++k) zst[w][t + 64 * k] = r[k];
    __syncthreads();   // the ONLY block barrier: sibling's stage visible

    // multiplier: pure mul/add + LDS mirror reads (short inter-FFT path)
#pragma unroll
    for (int k = 0; k < 8; ++k) {
        int ki = t + 64 * k;
        int mi = (HH - ki) & 511;
        float2 z  = r[k];                      // Z(k) (own spectrum, regs)
        float2 zc = zst[mw][mi];               // Z(-k) from mirror wave's stage
        float sx = sxk[k];
        float su  = sx * sx + sy * sy;
        float u2x = sx * sx - sy * sy;
        float u2y = 2.0f * sx * sy;
        float cx = zc.x, cy = -zc.y;           // conj(Z(-k))
        float tx = u2x * cx - u2y * cy;
        float ty = u2x * cy + u2y * cx;
        float bh = 0.5f * betak[k];
        r[k] = make_float2(bh * (su * z.x + tx), bh * (su * z.y + ty));
    }
    // no second barrier: inv FFT uses only wave-private b0[w]/b1[w]
    fft512<1>(r, tw, b0[w], b1[w], t);
    // COLUMN-major coalesced store (transpose deferred to kC's gather)
#pragma unroll
    for (int k = 0; k < 8; ++k) W1[cw * 512 + t + 64 * k] = r[k];
}

// --------------------------------------- phase C: inverse row FFT + output
__global__ __launch_bounds__(64) void kC(const float2* __restrict__ W1,
                                         const float* __restrict__ X,
                                         const float* __restrict__ F,
                                         float* __restrict__ out) {
    __shared__ float2 b0[PADDED], b1[PADDED];
    const int b = blockIdx.x, t = threadIdx.x;
    const int i = (b & 7) * 64 + (b >> 3);    // XCD x owns rows [64x,64x+64)
    float2 r[8];
    // row-gather from col-major W1 issued first (16-row cacheline groups
    // XCD-local); twiddle gen + stencil recompute hide under gather latency
#pragma unroll
    for (int m = 0; m < 8; ++m) r[m] = W1[(t + 64 * m) * 512 + i];
    Twid tw; make_tw(tw, t);
    float p0r[8], p1r[8];
    stencil_row(X, F, i, t, p0r, p1r);         // bitwise-identical to kA's p
    fft512<1>(r, tw, b0, b1, t);
#pragma unroll
    for (int k = 0; k < 8; ++k) {
        int j = t + 64 * k;
        __builtin_nontemporal_store(p0r[k] - r[k].x, &out[i * WW + j]);
        __builtin_nontemporal_store(p1r[k] - r[k].y, &out[NCELL + i * WW + j]);
    }
}

// ---------------------------------------------------------------------------
extern "C" void kernel_launch(void* const* d_in, const int* in_sizes, int n_in,
                              void* d_out, int out_size, void* d_ws, size_t ws_size,
                              hipStream_t stream) {
    const float* X = (const float*)d_in[1];
    const float* F = (const float*)d_in[2];
    float* out = (float*)d_out;
    float* ws  = (float*)d_ws;

    float2* Zt = (float2*)ws;                 // NCELL float2 (2 MB), row-major
    float2* W1 = Zt + NCELL;                  // NCELL float2 (2 MB), col-major

    kA<<<dim3(512), dim3(64),  0, stream>>>(X, F, Zt);
    kB<<<dim3(256), dim3(128), 0, stream>>>(Zt, W1);
    kC<<<dim3(512), dim3(64),  0, stream>>>(W1, X, F, out);
}